// Round 1
// baseline (1788.814 us; speedup 1.0000x reference)
//
#include <hip/hip_runtime.h>

namespace {
constexpr int kN    = 16;
constexpr int kCin  = 64;
constexpr int kL    = 2048;
constexpr int kV    = 25;
constexpr int kP    = 3;
constexpr int kCout = 64;
constexpr int kPC   = 192;   // P * C_out
constexpr int kKer  = 9;
constexpr int kTL   = 64;    // l's per block
constexpr int kXsC  = kL * kV;              // 51200
constexpr long kXsN = (long)kCin * kXsC;    // 3276800
}

// ws layout (floats): [0,12288) cwT[ci][pc] ; [12288,13888) bias2[c][w]
__global__ void stgcn_pre(const float* __restrict__ A,
                          const float* __restrict__ cw,
                          const float* __restrict__ cb,
                          float* __restrict__ ws) {
  int tid = blockIdx.x * blockDim.x + threadIdx.x;
  int nthr = gridDim.x * blockDim.x;
  for (int i = tid; i < kCin * kPC; i += nthr) {
    int ci = i / kPC, pc = i % kPC;
    ws[i] = cw[pc * kCin + ci];
  }
  for (int i = tid; i < kCout * kV; i += nthr) {
    int c = i / kV, w = i % kV;
    float s = 0.f;
    for (int p = 0; p < kP; ++p) {
      float as = 0.f;
      for (int v = 0; v < kV; ++v) as += A[(p * kV + v) * kV + w];
      s += cb[p * kCout + c] * as;
    }
    ws[kCin * kPC + i] = s;
  }
}

__global__ __launch_bounds__(256)
void stgcn_main(const float* __restrict__ x,
                const float* __restrict__ A,
                const float* __restrict__ ws,
                float* __restrict__ out) {
  __shared__ __align__(16) float sSx[kCin][26];     // sliding window sum (pad 26)
  __shared__ __align__(16) float sXc[kCin * kV];    // current x slice (residual reuse)
  __shared__ __align__(16) float sT[kPC][28];       // T[(p,c)][v], v padded to 28 (pad zeroed)
  __shared__ __align__(16) float sA[kP * kV * kV];  // raw A copy

  const int tid = threadIdx.x;
  const int n   = blockIdx.y;
  const int l0  = blockIdx.x * kTL;
  const float* cwT   = ws;                  // [64][192]
  const float* bias2 = ws + kCin * kPC;     // [64][25]
  const float* xn = x + n * kXsN;
  float* outn     = out + n * kXsN;

  for (int i = tid; i < kP * kV * kV; i += 256) sA[i] = A[i];
  for (int i = tid; i < kCin * 26; i += 256) (&sSx[0][0])[i] = 0.f;
  __syncthreads();

  // init: sSx = sum_{j=max(0,l0-9)}^{l0-1} x[j]   (invariant: window(l0-1) incl. the -9 term)
  {
    int jlo = l0 - kKer; if (jlo < 0) jlo = 0;
    for (int j = jlo; j < l0; ++j)
      for (int i = tid; i < kCin * kV; i += 256) {
        int ci = i / kV, v = i - ci * kV;
        sSx[ci][v] += xn[ci * kXsC + j * kV + v];
      }
  }
  // same-thread partition updates sSx again in U-phase; B1 below publishes.

  const int vs  = tid & 31;   // G1 v-slot (active < 25; 25..27 zero the pad)
  const int rg  = tid >> 5;   // G1 pc-group: pc = rg*24 + k
  const int w2  = vs;         // G2 w (active < 25)
  const int cb8 = rg * 8;     // G2 c base: c = cb8 + k

  for (int l = l0; l < l0 + kTL; ++l) {
    // ---- U: sliding-window update (+ stash residual slice) ----
    {
      const bool hasOld = (l - kKer) >= 0;
      for (int i = tid; i < kCin * kV; i += 256) {
        int ci = i / kV, v = i - ci * kV;
        const float* xp = xn + ci * kXsC + l * kV + v;
        float xv = xp[0];
        float xo = hasOld ? xp[-kKer * kV] : 0.f;
        sXc[i] = xv;
        sSx[ci][v] += xv - xo;
      }
    }
    __syncthreads();  // B1

    // ---- G1: T[(p,c)][v] = cwT[:, pc] . sSx[:, v] ----
    if (vs < kV) {
      float acc[24];
      #pragma unroll
      for (int k = 0; k < 24; ++k) acc[k] = 0.f;
      const float4* cw4base = reinterpret_cast<const float4*>(cwT) + rg * 6;
      #pragma unroll 2
      for (int ci = 0; ci < kCin; ++ci) {
        float s = sSx[ci][vs];
        const float4* row = cw4base + ci * 48;   // 192 floats = 48 float4 per ci row
        #pragma unroll
        for (int q = 0; q < 6; ++q) {
          float4 c4 = row[q];
          acc[4*q+0] = fmaf(c4.x, s, acc[4*q+0]);
          acc[4*q+1] = fmaf(c4.y, s, acc[4*q+1]);
          acc[4*q+2] = fmaf(c4.z, s, acc[4*q+2]);
          acc[4*q+3] = fmaf(c4.w, s, acc[4*q+3]);
        }
      }
      #pragma unroll
      for (int k = 0; k < 24; ++k) sT[rg * 24 + k][vs] = acc[k];
    } else if (vs < 28) {
      #pragma unroll
      for (int k = 0; k < 24; ++k) sT[rg * 24 + k][vs] = 0.f;  // zero pad cols (avoid NaN*0)
    }
    __syncthreads();  // B2

    // ---- G2 + epilogue: out[c][w] = sum_{p,v} T[(p,c)][v] * A[p][v][w] + cnt*bias2 + res ----
    if (w2 < kV) {
      float acc2[8];
      #pragma unroll
      for (int k = 0; k < 8; ++k) acc2[k] = 0.f;
      #pragma unroll
      for (int p = 0; p < kP; ++p) {
        float ar[28];
        #pragma unroll
        for (int v = 0; v < kV; ++v) ar[v] = sA[(p * kV + v) * kV + w2];
        ar[25] = 0.f; ar[26] = 0.f; ar[27] = 0.f;
        #pragma unroll
        for (int k = 0; k < 8; ++k) {
          const float4* tr = reinterpret_cast<const float4*>(&sT[p * kCout + cb8 + k][0]);
          float a = acc2[k];
          #pragma unroll
          for (int q = 0; q < 7; ++q) {
            float4 t = tr[q];
            a = fmaf(t.x, ar[4*q+0], a);
            a = fmaf(t.y, ar[4*q+1], a);
            a = fmaf(t.z, ar[4*q+2], a);
            a = fmaf(t.w, ar[4*q+3], a);
          }
          acc2[k] = a;
        }
      }
      float cnt = (float)((l + 1 < kKer) ? (l + 1) : kKer);
      #pragma unroll
      for (int k = 0; k < 8; ++k) {
        int c = cb8 + k;
        float val = fmaf(cnt, bias2[c * kV + w2], acc2[k]) + sXc[c * kV + w2];
        outn[c * kXsC + l * kV + w2] = fmaxf(val, 0.f);
      }
    }
    __syncthreads();  // B3
  }
}

extern "C" void kernel_launch(void* const* d_in, const int* in_sizes, int n_in,
                              void* d_out, int out_size, void* d_ws, size_t ws_size,
                              hipStream_t stream) {
  const float* x  = (const float*)d_in[0];
  const float* A  = (const float*)d_in[1];
  const float* cw = (const float*)d_in[2];
  const float* cb = (const float*)d_in[3];
  float* outp = (float*)d_out;
  float* ws   = (float*)d_ws;   // needs 13888 floats = 55.5 KB

  hipLaunchKernelGGL(stgcn_pre, dim3(16), dim3(256), 0, stream, A, cw, cb, ws);
  hipLaunchKernelGGL(stgcn_main, dim3(kL / kTL, kN), dim3(256), 0, stream,
                     x, A, ws, outp);
}

// Round 2
// 468.363 us; speedup vs baseline: 3.8193x; 3.8193x over previous
//
#include <hip/hip_runtime.h>

namespace {
constexpr int kL    = 2048;
constexpr int kV    = 25;
constexpr int kTL   = 8;          // l's per block
constexpr int kXsC  = kL * kV;                // 51200
constexpr long kXsN = 64L * kXsC;             // per-n stride

typedef __attribute__((ext_vector_type(8))) short  bf16x8;
typedef __attribute__((ext_vector_type(4))) float  f32x4;
typedef __attribute__((ext_vector_type(4))) unsigned short us4;

__device__ __forceinline__ float b2f(unsigned short u) {
  union { unsigned u32; float f; } x; x.u32 = ((unsigned)u) << 16; return x.f;
}
__device__ __forceinline__ unsigned short f2b(float f) {
  union { float f; unsigned u; } x; x.f = f;
  unsigned r = x.u + 0x7FFF + ((x.u >> 16) & 1);
  return (unsigned short)(r >> 16);
}
}

// ws layout (ushort elements unless noted):
//  [0, 12288)      s2 A-frags  bf16[4 mt][6 ksg][64 lane][8]   (W[c][k=p*64+ci])
//  [12288, 15360)  s1 B-frags  bf16[3 p][2 wt][64 lane][8]     (A[p][v][w], 0-padded)
//  byte 30720      bias2 fp32[64][25]
__global__ void stgcn_pre(const float* __restrict__ A,
                          const float* __restrict__ cw,
                          const float* __restrict__ cb,
                          unsigned short* __restrict__ wsu) {
  int t = threadIdx.x;
  // stage-2 A fragments
  for (int i = t; i < 4 * 6 * 64 * 8; i += 256) {
    int j = i & 7, lane = (i >> 3) & 63, ksg = (i >> 9) % 6, mt = i >> 9 == 0 ? 0 : (i >> 9) / 6;
    mt = (i >> 9) / 6;
    int c = 16 * mt + (lane & 15);
    int k = 32 * ksg + (lane >> 4) * 8 + j;
    int p = k >> 6, ci = k & 63;
    wsu[i] = f2b(cw[(p * 64 + c) * 64 + ci]);
  }
  // stage-1 B fragments
  for (int i = t; i < 3 * 2 * 64 * 8; i += 256) {
    int j = i & 7, lane = (i >> 3) & 63, wt = (i >> 9) & 1, p = i >> 10;
    int w = 16 * wt + (lane & 15);
    int v = (lane >> 4) * 8 + j;
    float val = (v < kV && w < kV) ? A[(p * kV + v) * kV + w] : 0.f;
    wsu[12288 + i] = f2b(val);
  }
  // bias2
  float* bias2 = (float*)((char*)wsu + 30720);
  for (int i = t; i < 64 * kV; i += 256) {
    int c = i / kV, w = i % kV;
    float s = 0.f;
    for (int p = 0; p < 3; ++p) {
      float as = 0.f;
      for (int v = 0; v < kV; ++v) as += A[(p * kV + v) * kV + w];
      s += cb[p * 64 + c] * as;
    }
    bias2[i] = s;
  }
}

__global__ __launch_bounds__(256, 1)
void stgcn_main(const float* __restrict__ x,
                const unsigned short* __restrict__ wsu,
                float* __restrict__ out) {
  // LDS: 57344 + 40960 + 29952 = 128256 B  -> 1 block/CU
  __shared__ unsigned short sXb[64 * 16 * 28];  // x tile bf16 [ci][li=0..15][v pad28]
  __shared__ unsigned short sSX[512 * 40];      // SX bf16 [m=ci*8+dl][v pad40], cols 25..31 zeroed
  __shared__ unsigned short sYs[208 * 72];      // Y  bf16 [nidx(l,w) pad208][ci pad72]

  const int t   = threadIdx.x;
  const int lam = t & 63;
  const int wid = t >> 6;
  const int lt  = blockIdx.x;
  const int nb  = blockIdx.y;
  const int l0  = lt * kTL;
  const float* xn = x + (long)nb * kXsN;
  float* outn     = out + (long)nb * kXsN;
  const float* bias2 = (const float*)((const char*)wsu + 30720);

  // ---- Phase 0: stage x[l0-8 .. l0+7] into LDS as bf16; zero Ys pad rows ----
  for (int i = t; i < 8 * 72; i += 256) sYs[200 * 72 + i] = 0;
  for (int it = 0; it < 25; ++it) {
    int tk = t + 256 * it;                 // 6400 tasks = 64 ci * 100 float4-chunks
    int ci = tk / 100, chunk = tk - 100 * ci;
    int g = 4 * chunk;                     // flat index in [0,400) = (li*25+v)
    float4 val;
    if (l0 == 0 && chunk < 50) {
      val = make_float4(0.f, 0.f, 0.f, 0.f);
    } else {
      long bg = (long)ci * kXsC + (long)(l0 - 8) * kV + g;
      val = *(const float4*)(xn + bg);
    }
    int li = g / 25, v = g - 25 * li;
    float vv[4] = {val.x, val.y, val.z, val.w};
    #pragma unroll
    for (int e = 0; e < 4; ++e) {
      sXb[(ci * 16 + li) * 28 + v] = f2b(vv[e]);
      if (++v == 25) { v = 0; ++li; }
    }
  }
  __syncthreads();

  // ---- Phase 1: sliding-window sums SX[m=(ci,dl)][v] (f32 acc, bf16 out) ----
  for (int half = 0; half < 2; ++half) {
    int it = t + 256 * half;               // 512 items = 64 ci * 8 v-quads
    int ci = it >> 3, q = it & 7;
    if (q == 7) {
      us4 z = {0, 0, 0, 0};
      for (int dl = 0; dl < kTL; ++dl)
        *(us4*)&sSX[(ci * 8 + dl) * 40 + 28] = z;
    } else {
      const unsigned short* xrow = &sXb[(ci * 16) * 28 + 4 * q];
      float a0 = 0, a1 = 0, a2 = 0, a3 = 0;
      #pragma unroll
      for (int j = 0; j < 9; ++j) {
        us4 u = *(const us4*)&xrow[j * 28];
        a0 += b2f(u.x); a1 += b2f(u.y); a2 += b2f(u.z); a3 += b2f(u.w);
      }
      for (int dl = 0; dl < kTL; ++dl) {
        us4 o;
        o.x = f2b(a0);
        o.y = (q == 6) ? (unsigned short)0 : f2b(a1);
        o.z = (q == 6) ? (unsigned short)0 : f2b(a2);
        o.w = (q == 6) ? (unsigned short)0 : f2b(a3);
        *(us4*)&sSX[(ci * 8 + dl) * 40 + 4 * q] = o;
        if (dl < kTL - 1) {
          us4 un = *(const us4*)&xrow[(dl + 9) * 28];
          us4 uo = *(const us4*)&xrow[dl * 28];
          a0 += b2f(un.x) - b2f(uo.x);
          a1 += b2f(un.y) - b2f(uo.y);
          a2 += b2f(un.z) - b2f(uo.z);
          a3 += b2f(un.w) - b2f(uo.w);
        }
      }
    }
  }
  __syncthreads();

  // ---- p-loop: stage1 (Y_p) then stage2 (es += W_p^T Y_p) ----
  f32x4 acc[13];
  #pragma unroll
  for (int nt = 0; nt < 13; ++nt) acc[nt] = (f32x4){0.f, 0.f, 0.f, 0.f};

  const int h   = lam >> 4;
  const int r16 = lam & 15;

  for (int p = 0; p < 3; ++p) {
    // stage 1: Y[nidx=(dl*25+w)][ci] = sum_v SX[(ci,dl)][v] * A[p][v][w]
    #pragma unroll
    for (int wt = 0; wt < 2; ++wt) {
      bf16x8 bf = *(const bf16x8*)&wsu[12288 + ((p * 2 + wt) * 64 + lam) * 8];
      int w = 16 * wt + r16;
      bool wok = (w < kV);
      #pragma unroll
      for (int i = 0; i < 8; ++i) {
        int mt = wid * 8 + i;
        bf16x8 af = *(const bf16x8*)&sSX[(16 * mt + r16) * 40 + 8 * h];
        f32x4 c0 = {0.f, 0.f, 0.f, 0.f};
        c0 = __builtin_amdgcn_mfma_f32_16x16x32_bf16(af, bf, c0, 0, 0, 0);
        if (wok) {
          int mb = 16 * mt + 4 * h;
          int ci = mb >> 3, dl0 = mb & 7;
          #pragma unroll
          for (int r = 0; r < 4; ++r)
            sYs[((dl0 + r) * kV + w) * 72 + ci] = f2b(c0[r]);
        }
      }
    }
    __syncthreads();

    // stage 2: es[c][nidx] += sum_ci W[c][p*64+ci] * Y[nidx][ci]
    #pragma unroll
    for (int ksl = 0; ksl < 2; ++ksl) {
      bf16x8 wf = *(const bf16x8*)&wsu[((wid * 6 + p * 2 + ksl) * 64 + lam) * 8];
      #pragma unroll
      for (int nt = 0; nt < 13; ++nt) {
        bf16x8 yf = *(const bf16x8*)&sYs[(16 * nt + r16) * 72 + 32 * ksl + 8 * h];
        acc[nt] = __builtin_amdgcn_mfma_f32_16x16x32_bf16(wf, yf, acc[nt], 0, 0, 0);
      }
    }
    __syncthreads();   // before next p overwrites Ys
  }

  // ---- Epilogue: + cnt*bias2 + residual, ReLU, store ----
  const int cbase = 16 * wid + 4 * h;
  #pragma unroll
  for (int nt = 0; nt < 13; ++nt) {
    int nidx = 16 * nt + r16;
    if (nidx < 200) {
      int dl = nidx / 25, wv = nidx - 25 * dl;
      float cnt = (l0 == 0) ? (float)((l0 + dl + 1 < 9) ? l0 + dl + 1 : 9) : 9.f;
      #pragma unroll
      for (int r = 0; r < 4; ++r) {
        int c = cbase + r;
        float val = acc[nt][r] + cnt * bias2[c * kV + wv]
                  + b2f(sXb[(c * 16 + dl + 8) * 28 + wv]);
        outn[(long)c * kXsC + (long)(l0 + dl) * kV + wv] = fmaxf(val, 0.f);
      }
    }
  }
}

extern "C" void kernel_launch(void* const* d_in, const int* in_sizes, int n_in,
                              void* d_out, int out_size, void* d_ws, size_t ws_size,
                              hipStream_t stream) {
  const float* x  = (const float*)d_in[0];
  const float* A  = (const float*)d_in[1];
  const float* cw = (const float*)d_in[2];
  const float* cb = (const float*)d_in[3];
  unsigned short* wsu = (unsigned short*)d_ws;   // needs 37120 B

  hipLaunchKernelGGL(stgcn_pre, dim3(1), dim3(256), 0, stream, A, cw, cb, wsu);
  hipLaunchKernelGGL(stgcn_main, dim3(kL / kTL, 16), dim3(256), 0, stream,
                     x, wsu, (float*)d_out);
}

// Round 3
// 277.134 us; speedup vs baseline: 6.4547x; 1.6900x over previous
//
#include <hip/hip_runtime.h>

namespace {
constexpr int kL    = 2048;
constexpr int kV    = 25;
constexpr int kTL   = 8;
constexpr int kXsC  = kL * kV;          // 51200
constexpr long kXsN = 64L * kXsC;

typedef __attribute__((ext_vector_type(8))) short  bf16x8;
typedef __attribute__((ext_vector_type(4))) float  f32x4;
typedef __attribute__((ext_vector_type(4))) unsigned short us4;

__device__ __forceinline__ float b2f(unsigned short u) {
  union { unsigned u32; float f; } x; x.u32 = ((unsigned)u) << 16; return x.f;
}
__device__ __forceinline__ unsigned short f2b(float f) {
  union { float f; unsigned u; } x; x.f = f;
  unsigned r = x.u + 0x7FFF + ((x.u >> 16) & 1);
  return (unsigned short)(r >> 16);
}
}

// ws layout (ushort):
//  [0, 12288)      stage-2 A-frags bf16[4 mt][6 ksg][64 lane][8]   (W[c][k=p*64+ci])
//  [12288, 15360)  stage-1 B-frags bf16[3 p][2 wt][64 lane][8]     (A[p][v][w], 0-pad)
//  byte 30720      bias2 fp32[64][25]
__global__ void stgcn_pre(const float* __restrict__ A,
                          const float* __restrict__ cw,
                          const float* __restrict__ cb,
                          unsigned short* __restrict__ wsu) {
  int t = threadIdx.x;
  for (int i = t; i < 4 * 6 * 64 * 8; i += 256) {
    int j = i & 7, lane = (i >> 3) & 63;
    int rem = i >> 9;              // 0..23
    int ksg = rem % 6, mt = rem / 6;
    int c = 16 * mt + (lane & 15);
    int k = 32 * ksg + (lane >> 4) * 8 + j;
    int p = k >> 6, ci = k & 63;
    wsu[i] = f2b(cw[(p * 64 + c) * 64 + ci]);
  }
  for (int i = t; i < 3 * 2 * 64 * 8; i += 256) {
    int j = i & 7, lane = (i >> 3) & 63, wt = (i >> 9) & 1, p = i >> 10;
    int w = 16 * wt + (lane & 15);
    int v = (lane >> 4) * 8 + j;
    float val = (v < kV && w < kV) ? A[(p * kV + v) * kV + w] : 0.f;
    wsu[12288 + i] = f2b(val);
  }
  float* bias2 = (float*)((char*)wsu + 30720);
  for (int i = t; i < 64 * kV; i += 256) {
    int c = i / kV, w = i % kV;
    float s = 0.f;
    for (int p = 0; p < 3; ++p) {
      float as = 0.f;
      for (int v = 0; v < kV; ++v) as += A[(p * kV + v) * kV + w];
      s += cb[p * 64 + c] * as;
    }
    bias2[i] = s;
  }
}

__global__ __launch_bounds__(512, 4)
void stgcn_main(const float* __restrict__ x,
                const unsigned short* __restrict__ wsu,
                float* __restrict__ out) {
  // LDS: 40960 + 29952 = 70912 B -> 2 blocks/CU
  __shared__ unsigned short sSX[512 * 40];  // SX bf16 [m=ci*8+dl][v 32 + pad8], 8-col blocks XOR-swizzled by ci&3
  __shared__ unsigned short sYs[208 * 72];  // Y  bf16 [nidx(dl,w) pad208][ci pad72]

  const int t   = threadIdx.x;
  const int lam = t & 63;
  const int wid = t >> 6;               // 0..7
  const int l0  = blockIdx.x * kTL;
  const float* xn = x + (long)blockIdx.y * kXsN;
  float* outn     = out + (long)blockIdx.y * kXsN;
  const float* bias2 = (const float*)((const char*)wsu + 30720);

  // zero sYs pad rows (200..207)
  for (int i = t; i < 8 * 72; i += 512) sYs[200 * 72 + i] = 0;

  // ---- SX phase: rolling window sums, global -> regs -> LDS (bf16) ----
  {
    const int ci = t >> 3, q = t & 7;
    const int rowb = ci * 8 * 40;
    if (q == 7) {
      const int c4 = ((3 ^ (ci & 3)) << 3) | 4;   // logical col 28
      us4 z = {0, 0, 0, 0};
      #pragma unroll
      for (int dl = 0; dl < 8; ++dl) *(us4*)&sSX[rowb + dl * 40 + c4] = z;
    } else {
      const int colL = 4 * q;
      const int c4 = (((colL >> 3) ^ (ci & 3)) << 3) | (colL & 7);
      const float* xr = xn + (long)ci * kXsC + (long)(l0 - 8) * kV + colL;
      const bool full = (q < 6);                  // q==6 -> only v=24 valid
      float a0 = 0.f, a1 = 0.f, a2 = 0.f, a3 = 0.f;
      if (l0) {
        #pragma unroll
        for (int j = 0; j < 9; ++j) {
          const float* r = xr + j * kV;
          a0 += r[0];
          if (full) { a1 += r[1]; a2 += r[2]; a3 += r[3]; }
        }
      } else {
        const float* r = xr + 8 * kV;
        a0 = r[0];
        if (full) { a1 = r[1]; a2 = r[2]; a3 = r[3]; }
      }
      #pragma unroll
      for (int dl = 0; dl < 8; ++dl) {
        us4 o = { f2b(a0), f2b(a1), f2b(a2), f2b(a3) };
        *(us4*)&sSX[rowb + dl * 40 + c4] = o;
        if (dl < 7) {
          const float* pn = xr + (dl + 9) * kV;
          a0 += pn[0];
          if (full) { a1 += pn[1]; a2 += pn[2]; a3 += pn[3]; }
          if (l0) {
            const float* po = xr + dl * kV;
            a0 -= po[0];
            if (full) { a1 -= po[1]; a2 -= po[2]; a3 -= po[3]; }
          }
        }
      }
    }
  }
  __syncthreads();

  // ---- p-loop: stage1 (Y_p to sYs) then stage2 (acc += W_p^T Y_p) ----
  f32x4 acc[7];
  #pragma unroll
  for (int nt = 0; nt < 7; ++nt) acc[nt] = (f32x4){0.f, 0.f, 0.f, 0.f};

  const int h   = lam >> 4;
  const int r16 = lam & 15;
  const int nh  = wid >> 2;       // stage2: n-half
  const int mt2 = wid & 3;        // stage2: m-tile (c block)
  const int ntb = nh ? 7 : 0;

  for (int p = 0; p < 3; ++p) {
    // stage 1: Y[(dl*25+w)][ci] = sum_v SX[(ci,dl)][v] * A[p][v][w]
    #pragma unroll
    for (int wt = 0; wt < 2; ++wt) {
      bf16x8 bf = *(const bf16x8*)&wsu[12288 + ((p * 2 + wt) * 64 + lam) * 8];
      int w = 16 * wt + r16;
      bool wok = (w < kV);
      #pragma unroll
      for (int i = 0; i < 4; ++i) {
        int mt = wid * 4 + i;
        int m  = 16 * mt + r16;
        int cia = m >> 3;
        bf16x8 af = *(const bf16x8*)&sSX[m * 40 + ((h ^ (cia & 3)) << 3)];
        f32x4 c0 = {0.f, 0.f, 0.f, 0.f};
        c0 = __builtin_amdgcn_mfma_f32_16x16x32_bf16(af, bf, c0, 0, 0, 0);
        if (wok) {
          int mb = 16 * mt + 4 * h;
          int cw_ = mb >> 3, dl0 = mb & 7;
          #pragma unroll
          for (int r = 0; r < 4; ++r)
            sYs[((dl0 + r) * kV + w) * 72 + cw_] = f2b(c0[r]);
        }
      }
    }
    __syncthreads();

    // stage 2: es[c][nidx] += sum_ci W[c][p*64+ci] * Y[nidx][ci]
    #pragma unroll
    for (int ksl = 0; ksl < 2; ++ksl) {
      bf16x8 wf = *(const bf16x8*)&wsu[((mt2 * 6 + p * 2 + ksl) * 64 + lam) * 8];
      #pragma unroll
      for (int nt = 0; nt < 7; ++nt) {
        if (nh == 0 || nt < 6) {
          bf16x8 yf = *(const bf16x8*)&sYs[(16 * (ntb + nt) + r16) * 72 + 32 * ksl + 8 * h];
          acc[nt] = __builtin_amdgcn_mfma_f32_16x16x32_bf16(wf, yf, acc[nt], 0, 0, 0);
        }
      }
    }
    if (p < 2) __syncthreads();
  }

  // ---- Epilogue: + cnt*bias2 + residual (global, cache-hot), ReLU, store ----
  const int cb4 = 16 * mt2 + 4 * h;
  #pragma unroll
  for (int nt = 0; nt < 7; ++nt) {
    if (nh == 0 || nt < 6) {
      int nidx = 16 * (ntb + nt) + r16;
      if (nidx < 200) {
        int dl = nidx / 25, wv = nidx - 25 * dl;
        float cnt = l0 ? 9.f : (float)(dl + 1);
        long base = (long)(l0 + dl) * kV + wv;
        #pragma unroll
        for (int r = 0; r < 4; ++r) {
          int c = cb4 + r;
          float val = acc[nt][r] + cnt * bias2[c * kV + wv] + xn[(long)c * kXsC + base];
          outn[(long)c * kXsC + base] = fmaxf(val, 0.f);
        }
      }
    }
  }
}

extern "C" void kernel_launch(void* const* d_in, const int* in_sizes, int n_in,
                              void* d_out, int out_size, void* d_ws, size_t ws_size,
                              hipStream_t stream) {
  const float* x  = (const float*)d_in[0];
  const float* A  = (const float*)d_in[1];
  const float* cw = (const float*)d_in[2];
  const float* cb = (const float*)d_in[3];
  unsigned short* wsu = (unsigned short*)d_ws;   // needs 37120 B

  hipLaunchKernelGGL(stgcn_pre, dim3(1), dim3(256), 0, stream, A, cw, cb, wsu);
  hipLaunchKernelGGL(stgcn_main, dim3(kL / kTL, 16), dim3(512), 0, stream,
                     x, wsu, (float*)d_out);
}